// Round 3
// 484.036 us; speedup vs baseline: 1.0223x; 1.0223x over previous
//
#include <hip/hip_runtime.h>

typedef short short8 __attribute__((ext_vector_type(8)));
typedef short short4v __attribute__((ext_vector_type(4)));
typedef float f32x4 __attribute__((ext_vector_type(4)));

#define B_ROWS 16384
#define SCALE 1.4285714285714286f   // f32 round of 1/0.7, same as np

__device__ __forceinline__ float bf2f(unsigned short u) {
    return __uint_as_float(((unsigned)u) << 16);
}
__device__ __forceinline__ unsigned short f2bf(float f) {
    unsigned u = __float_as_uint(f);
    u += 0x7fffu + ((u >> 16) & 1u);   // RNE
    return (unsigned short)(u >> 16);
}

__device__ __forceinline__ void gl_lds16(const void* g, void* l) {
    __builtin_amdgcn_global_load_lds(
        (const __attribute__((address_space(1))) unsigned int*)g,
        (__attribute__((address_space(3))) unsigned int*)l, 16, 0, 0);
}

__device__ __forceinline__ float wave_max(float v) {
    #pragma unroll
    for (int m = 1; m < 64; m <<= 1) v = fmaxf(v, __shfl_xor(v, m, 64));
    return v;
}
__device__ __forceinline__ float wave_sum(float v) {
    #pragma unroll
    for (int m = 1; m < 64; m <<= 1) v += __shfl_xor(v, m, 64);
    return v;
}

// ---- prep: W1 f32 (4096x128) -> transposed bf16 hi/lo splits (128x4096) ----
// (unchanged — numerics anchor)
__global__ void k_prep(const float* __restrict__ w1,
                       unsigned short* __restrict__ w1h,
                       unsigned short* __restrict__ w1l) {
    int tid = blockIdx.x * 256 + threadIdx.x;     // 524288 total
    int n = tid >> 12, k = tid & 4095;
    float v = w1[k * 128 + n];
    unsigned short hi = f2bf(v);
    w1h[tid] = hi;
    w1l[tid] = f2bf(v - bf2f(hi));
}

// ---- fused: GEMM1 (split-bf16 3-pass MFMA) + logits + stats, one kernel ---
// 512 threads = 8 waves; each wave owns a 32x16 slice of the 32x128 h tile.
// 80 KB LDS -> 2 blocks/CU -> 4 waves/SIMD during the GEMM phase (was 2).
// Phase 2 aliases the staging LDS: hbuf (16 KB) over sA, lgs (40 KB) over sB.
__global__ __launch_bounds__(512, 4) void k_fused(
        const float* __restrict__ x,
        const unsigned short* __restrict__ w1h,
        const unsigned short* __restrict__ w1l,
        const float* __restrict__ b1,
        const float* __restrict__ w2,
        const float* __restrict__ b2,
        const float* __restrict__ m1,
        const float* __restrict__ m2,
        float* __restrict__ out) {
    __shared__ __attribute__((aligned(128))) char smem[81920];
    unsigned short* sAh0 = (unsigned short*)smem;            // [2][32*64]  8 KB
    unsigned short* sAl0 = (unsigned short*)(smem + 8192);   //             8 KB
    unsigned short* sBh0 = (unsigned short*)(smem + 16384);  // [2][128*64] 32 KB
    unsigned short* sBl0 = (unsigned short*)(smem + 49152);  //             32 KB
    float* hbuf = (float*)smem;                              // phase2: 32x128 f32
    float* lgs  = (float*)(smem + 16384);                    // phase2: 5*32*64 f32

    const int t = threadIdx.x;
    const int w = t >> 6, lane = t & 63;
    const int l15 = lane & 15, l4 = lane >> 4;
    const int rowBase = blockIdx.x << 5;

    // ================= phase 1: h = relu(x @ W1 + b1) =================
    const int am = t >> 4;              // A-stage row 0..31
    const int rem = t & 15;             // A-stage k-quad 0..15
    const int aDst = (((am << 3) + ((rem >> 1) ^ (am & 7))) << 3) + ((rem & 1) << 2);

    f32x4 acc[2];
    #pragma unroll
    for (int mf = 0; mf < 2; ++mf) {
        f32x4 z = {0.f, 0.f, 0.f, 0.f};
        acc[mf] = z;
    }

    auto stageB = [&](int buf, int k0) {
        #pragma unroll
        for (int j = 0; j < 2; ++j) {
            int c = (j << 9) + t;                 // 0..1023
            int n = c >> 3;
            int cl = (c & 7) ^ (n & 7);
            const size_t go = (size_t)n * 4096 + k0 + (cl << 3);
            gl_lds16(w1h + go, sBh0 + (buf << 13) + (c << 3));
            gl_lds16(w1l + go, sBl0 + (buf << 13) + (c << 3));
        }
    };
    auto loadA = [&](int k0) {
        return *(const float4*)(x + ((size_t)(rowBase + am) << 12) + k0 + (rem << 2));
    };
    auto writeA = [&](int buf, float4 a0) {
        float av[4] = {a0.x, a0.y, a0.z, a0.w};
        short4v H, L;
        #pragma unroll
        for (int i = 0; i < 4; ++i) {
            unsigned short hi = f2bf(av[i]);
            H[i] = (short)hi;
            L[i] = (short)f2bf(av[i] - bf2f(hi));
        }
        *(short4v*)(sAh0 + (buf << 11) + aDst) = H;
        *(short4v*)(sAl0 + (buf << 11) + aDst) = L;
    };

    stageB(0, 0);
    writeA(0, loadA(0));
    __syncthreads();

    for (int it = 0; it < 64; ++it) {
        const int buf = it & 1;
        const bool pf = (it + 1 < 64);
        float4 aN = make_float4(0.f, 0.f, 0.f, 0.f);
        if (pf) {
            stageB(buf ^ 1, (it + 1) << 6);   // gl_lds issues, lands by barrier
            aN = loadA((it + 1) << 6);        // issue x load BEFORE compute
        }
        #pragma unroll
        for (int ks = 0; ks < 2; ++ks) {
            short8 ah[2], al[2], bh, bl;
            #pragma unroll
            for (int mf = 0; mf < 2; ++mf) {
                int rm = (mf << 4) + l15;
                int pc = ((ks << 2) + l4) ^ (rm & 7);
                int o = ((rm << 3) + pc) << 3;
                ah[mf] = *(const short8*)(sAh0 + (buf << 11) + o);
                al[mf] = *(const short8*)(sAl0 + (buf << 11) + o);
            }
            {
                int rn = (w << 4) + l15;
                int pc = ((ks << 2) + l4) ^ (rn & 7);
                int o = ((rn << 3) + pc) << 3;
                bh = *(const short8*)(sBh0 + (buf << 13) + o);
                bl = *(const short8*)(sBl0 + (buf << 13) + o);
            }
            #pragma unroll
            for (int mf = 0; mf < 2; ++mf) {
                acc[mf] = __builtin_amdgcn_mfma_f32_16x16x32_bf16(ah[mf], bh, acc[mf], 0, 0, 0);
                acc[mf] = __builtin_amdgcn_mfma_f32_16x16x32_bf16(ah[mf], bl, acc[mf], 0, 0, 0);
                acc[mf] = __builtin_amdgcn_mfma_f32_16x16x32_bf16(al[mf], bh, acc[mf], 0, 0, 0);
            }
        }
        if (pf) writeA(buf ^ 1, aN);          // convert+ds_write AFTER compute
        __syncthreads();
    }

    // epilogue: bias + relu -> LDS hbuf, XOR-swizzled packs (4 rows/wave
    // broadcast reads in phase 2 land on distinct bank quads)
    {
        const int col = (w << 4) + l15;
        const float bias = b1[col];
        #pragma unroll
        for (int mf = 0; mf < 2; ++mf) {
            const int rbase = (mf << 4) + (l4 << 2);
            #pragma unroll
            for (int rr = 0; rr < 4; ++rr) {
                const int r = rbase + rr;
                float v = acc[mf][rr] + bias;
                v = v > 0.f ? v : 0.f;
                hbuf[r * 128 + (col ^ ((r & 7) << 2))] = v;
            }
        }
    }
    __syncthreads();

    // ================= phase 2: logits (h from LDS) =================
    const int lr = t >> 4;               // local row 0..31
    const int eg = t & 15;               // expert group (4 experts)
    const int e0 = eg << 2;
    const int row = rowBase + lr;
    const int lsw = (lr & 7) << 2;

    float acc2[5][4];
    #pragma unroll
    for (int s = 0; s < 5; ++s)
        #pragma unroll
        for (int e = 0; e < 4; ++e) acc2[s][e] = 0.f;

    const float* hrow = hbuf + lr * 128;
    const size_t m1row = ((size_t)row) << 7;

    for (int k = 0; k < 128; k += 4) {
        float4 h4 = *(const float4*)(hrow + (k ^ lsw));
        float hv[4] = {h4.x, h4.y, h4.z, h4.w};
        float w2v[4][4];
        #pragma unroll
        for (int kk = 0; kk < 4; ++kk) {
            float4 wa = *(const float4*)(w2 + ((k + kk) << 6) + e0);
            w2v[kk][0] = wa.x; w2v[kk][1] = wa.y; w2v[kk][2] = wa.z; w2v[kk][3] = wa.w;
        }
        #pragma unroll
        for (int s = 0; s < 5; ++s) {
            float4 mu = *(const float4*)(m1 + (size_t)s * (B_ROWS * 128) + m1row + k);
            float hd[4];
            hd[0] = (mu.x >= 0.3f) ? hv[0] * SCALE : 0.f;
            hd[1] = (mu.y >= 0.3f) ? hv[1] * SCALE : 0.f;
            hd[2] = (mu.z >= 0.3f) ? hv[2] * SCALE : 0.f;
            hd[3] = (mu.w >= 0.3f) ? hv[3] * SCALE : 0.f;
            #pragma unroll
            for (int kk = 0; kk < 4; ++kk)     // k ascending: same order as R2
                #pragma unroll
                for (int e = 0; e < 4; ++e)
                    acc2[s][e] += hd[kk] * w2v[kk][e];
        }
    }

    // +b2, mask2*scale, park in lgs
    {
        float4 ba = *(const float4*)(b2 + e0);
        float bv4[4] = {ba.x, ba.y, ba.z, ba.w};
        #pragma unroll
        for (int s = 0; s < 5; ++s) {
            const float* m2p = m2 + ((size_t)s * B_ROWS + row) * 64 + e0;
            float4 ma = *(const float4*)m2p;
            float mk[4] = {ma.x, ma.y, ma.z, ma.w};
            float lv[4];
            #pragma unroll
            for (int e = 0; e < 4; ++e) {
                float v = acc2[s][e] + bv4[e];
                lv[e] = (mk[e] >= 0.3f) ? v * SCALE : 0.f;
            }
            *(float4*)(lgs + ((s << 5) + lr) * 64 + e0) =
                make_float4(lv[0], lv[1], lv[2], lv[3]);
        }
    }
    __syncthreads();

    // ================= phase 3: stats, wave per 4 rows =================
    for (int r4 = 0; r4 < 4; ++r4) {
        const int r = (w << 2) + r4;
        float l[5], p[5];
        #pragma unroll
        for (int s = 0; s < 5; ++s)
            l[s] = lgs[((s << 5) + r) * 64 + lane];

        float ml = ((((l[0] + l[1]) + l[2]) + l[3]) + l[4]) / 5.0f;

        #pragma unroll
        for (int s = 0; s < 5; ++s) {
            float mx = wave_max(l[s]);
            float ev = expf(l[s] - mx);
            float sm = wave_sum(ev);
            p[s] = ev / sm;
        }

        float mx = wave_max(ml);
        float ev = expf(ml - mx);
        float sm = wave_sum(ev);
        float prob = ev / sm;

        float mean = ((((p[0] + p[1]) + p[2]) + p[3]) + p[4]) / 5.0f;
        float var = 0.f;
        #pragma unroll
        for (int s = 0; s < 5; ++s) { float d = p[s] - mean; var += d * d; }
        float sd = sqrtf(var * 0.25f);
        float unc = wave_sum(sd) / 64.0f;

        float pv = prob;
        float vv[4]; int vi[4];
        #pragma unroll
        for (int q = 0; q < 4; ++q) {
            float bvx = pv; int bi = lane;
            #pragma unroll
            for (int m = 1; m < 64; m <<= 1) {
                float ov = __shfl_xor(bvx, m, 64);
                int oi = __shfl_xor(bi, m, 64);
                if (ov > bvx || (ov == bvx && oi < bi)) { bvx = ov; bi = oi; }
            }
            vv[q] = bvx; vi[q] = bi;
            if (lane == bi) pv = -1.f;
        }

        if (lane == 0) {
            int grow = rowBase + r;
            bool ug = unc > 0.3f;
            float4 fi = make_float4((float)vi[0], (float)vi[1],
                                    ug ? (float)vi[2] : -1.f,
                                    ug ? (float)vi[3] : -1.f);
            *(float4*)(out + (size_t)grow * 4) = fi;
            float4 fp = make_float4(vv[0], vv[1],
                                    ug ? vv[2] : 0.f,
                                    ug ? vv[3] : 0.f);
            *(float4*)(out + 65536 + (size_t)grow * 4) = fp;
            out[131072 + grow] = unc;
        }
    }
}

extern "C" void kernel_launch(void* const* d_in, const int* in_sizes, int n_in,
                              void* d_out, int out_size, void* d_ws, size_t ws_size,
                              hipStream_t stream) {
    const float* x  = (const float*)d_in[0];
    const float* W1 = (const float*)d_in[1];
    const float* b1 = (const float*)d_in[2];
    const float* W2 = (const float*)d_in[3];
    const float* b2 = (const float*)d_in[4];
    const float* m1 = (const float*)d_in[5];
    const float* m2 = (const float*)d_in[6];
    float* out = (float*)d_out;
    char* ws = (char*)d_ws;

    unsigned short* w1h = (unsigned short*)ws;                // 1 MB
    unsigned short* w1l = (unsigned short*)(ws + (1 << 20));  // 1 MB

    k_prep <<<2048, 256, 0, stream>>>(W1, w1h, w1l);
    k_fused<<<512,  512, 0, stream>>>(x, w1h, w1l, b1, W2, b2, m1, m2, out);
}

// Round 4
// 470.126 us; speedup vs baseline: 1.0525x; 1.0296x over previous
//
#include <hip/hip_runtime.h>

typedef short short8 __attribute__((ext_vector_type(8)));
typedef short short4v __attribute__((ext_vector_type(4)));
typedef float f32x4 __attribute__((ext_vector_type(4)));

#define B_ROWS 16384
#define SCALE 1.4285714285714286f   // f32 round of 1/0.7, same as np

__device__ __forceinline__ float bf2f(unsigned short u) {
    return __uint_as_float(((unsigned)u) << 16);
}
__device__ __forceinline__ unsigned short f2bf(float f) {
    unsigned u = __float_as_uint(f);
    u += 0x7fffu + ((u >> 16) & 1u);   // RNE
    return (unsigned short)(u >> 16);
}

__device__ __forceinline__ void gl_lds16(const void* g, void* l) {
    __builtin_amdgcn_global_load_lds(
        (const __attribute__((address_space(1))) unsigned int*)g,
        (__attribute__((address_space(3))) unsigned int*)l, 16, 0, 0);
}

__device__ __forceinline__ float wave_max(float v) {
    #pragma unroll
    for (int m = 1; m < 64; m <<= 1) v = fmaxf(v, __shfl_xor(v, m, 64));
    return v;
}
__device__ __forceinline__ float wave_sum(float v) {
    #pragma unroll
    for (int m = 1; m < 64; m <<= 1) v += __shfl_xor(v, m, 64);
    return v;
}

// ---- prep: W1 f32 (4096x128) -> transposed bf16 hi/lo splits (128x4096) ----
__global__ void k_prep(const float* __restrict__ w1,
                       unsigned short* __restrict__ w1h,
                       unsigned short* __restrict__ w1l) {
    int tid = blockIdx.x * 256 + threadIdx.x;     // 524288 total
    int n = tid >> 12, k = tid & 4095;
    float v = w1[k * 128 + n];
    unsigned short hi = f2bf(v);
    w1h[tid] = hi;
    w1l[tid] = f2bf(v - bf2f(hi));
}

// ---- fused: GEMM1 + logits + stats. Phase 1 unchanged from R3.
// Phase 2 restructured: per sample-pair, masked activations hm staged to LDS
// in bulk (coalesced m1 stream), W2 staged to LDS once; FMA inner loop is
// pure-LDS (no global loads, no vmcnt stalls). Math order bit-identical.
// LDS map (81920 B):
//   phase1: sAh[0:8K) sAl[8K:16K) sBh[16K:48K) sBl[48K:80K)
//   phase2: hbuf[0:16K) hm[16K:48K) w2s[48K:80K)
//   phase2 tail/phase3: lgs[16K:56K)  (aliases hm+w2s head, barrier-guarded)
__global__ __launch_bounds__(512, 4) void k_fused(
        const float* __restrict__ x,
        const unsigned short* __restrict__ w1h,
        const unsigned short* __restrict__ w1l,
        const float* __restrict__ b1,
        const float* __restrict__ w2,
        const float* __restrict__ b2,
        const float* __restrict__ m1,
        const float* __restrict__ m2,
        float* __restrict__ out) {
    __shared__ __attribute__((aligned(128))) char smem[81920];
    unsigned short* sAh0 = (unsigned short*)smem;            // [2][32*64]  8 KB
    unsigned short* sAl0 = (unsigned short*)(smem + 8192);   //             8 KB
    unsigned short* sBh0 = (unsigned short*)(smem + 16384);  // [2][128*64] 32 KB
    unsigned short* sBl0 = (unsigned short*)(smem + 49152);  //             32 KB
    float* hbuf = (float*)smem;                              // 32x128 f32, 16 KB
    float* hmb  = (float*)(smem + 16384);                    // [2][32*128] 32 KB
    float* w2s  = (float*)(smem + 49152);                    // [128][64]   32 KB
    float* lgs  = (float*)(smem + 16384);                    // 5*32*64 f32 40 KB

    const int t = threadIdx.x;
    const int w = t >> 6, lane = t & 63;
    const int l15 = lane & 15, l4 = lane >> 4;
    const int rowBase = blockIdx.x << 5;

    // ================= phase 1: h = relu(x @ W1 + b1) =================
    const int am = t >> 4;              // A-stage row 0..31
    const int rem = t & 15;             // A-stage k-quad 0..15
    const int aDst = (((am << 3) + ((rem >> 1) ^ (am & 7))) << 3) + ((rem & 1) << 2);

    f32x4 acc[2];
    #pragma unroll
    for (int mf = 0; mf < 2; ++mf) {
        f32x4 z = {0.f, 0.f, 0.f, 0.f};
        acc[mf] = z;
    }

    auto stageB = [&](int buf, int k0) {
        #pragma unroll
        for (int j = 0; j < 2; ++j) {
            int c = (j << 9) + t;                 // 0..1023
            int n = c >> 3;
            int cl = (c & 7) ^ (n & 7);
            const size_t go = (size_t)n * 4096 + k0 + (cl << 3);
            gl_lds16(w1h + go, sBh0 + (buf << 13) + (c << 3));
            gl_lds16(w1l + go, sBl0 + (buf << 13) + (c << 3));
        }
    };
    auto loadA = [&](int k0) {
        return *(const float4*)(x + ((size_t)(rowBase + am) << 12) + k0 + (rem << 2));
    };
    auto writeA = [&](int buf, float4 a0) {
        float av[4] = {a0.x, a0.y, a0.z, a0.w};
        short4v H, L;
        #pragma unroll
        for (int i = 0; i < 4; ++i) {
            unsigned short hi = f2bf(av[i]);
            H[i] = (short)hi;
            L[i] = (short)f2bf(av[i] - bf2f(hi));
        }
        *(short4v*)(sAh0 + (buf << 11) + aDst) = H;
        *(short4v*)(sAl0 + (buf << 11) + aDst) = L;
    };

    stageB(0, 0);
    writeA(0, loadA(0));
    __syncthreads();

    for (int it = 0; it < 64; ++it) {
        const int buf = it & 1;
        const bool pf = (it + 1 < 64);
        float4 aN = make_float4(0.f, 0.f, 0.f, 0.f);
        if (pf) {
            stageB(buf ^ 1, (it + 1) << 6);   // gl_lds issues, lands by barrier
            aN = loadA((it + 1) << 6);        // issue x load BEFORE compute
        }
        #pragma unroll
        for (int ks = 0; ks < 2; ++ks) {
            short8 ah[2], al[2], bh, bl;
            #pragma unroll
            for (int mf = 0; mf < 2; ++mf) {
                int rm = (mf << 4) + l15;
                int pc = ((ks << 2) + l4) ^ (rm & 7);
                int o = ((rm << 3) + pc) << 3;
                ah[mf] = *(const short8*)(sAh0 + (buf << 11) + o);
                al[mf] = *(const short8*)(sAl0 + (buf << 11) + o);
            }
            {
                int rn = (w << 4) + l15;
                int pc = ((ks << 2) + l4) ^ (rn & 7);
                int o = ((rn << 3) + pc) << 3;
                bh = *(const short8*)(sBh0 + (buf << 13) + o);
                bl = *(const short8*)(sBl0 + (buf << 13) + o);
            }
            #pragma unroll
            for (int mf = 0; mf < 2; ++mf) {
                acc[mf] = __builtin_amdgcn_mfma_f32_16x16x32_bf16(ah[mf], bh, acc[mf], 0, 0, 0);
                acc[mf] = __builtin_amdgcn_mfma_f32_16x16x32_bf16(ah[mf], bl, acc[mf], 0, 0, 0);
                acc[mf] = __builtin_amdgcn_mfma_f32_16x16x32_bf16(al[mf], bh, acc[mf], 0, 0, 0);
            }
        }
        if (pf) writeA(buf ^ 1, aN);          // convert+ds_write AFTER compute
        __syncthreads();
    }

    // epilogue: bias + relu -> LDS hbuf, XOR-swizzled ((r&7)<<2 on float col)
    {
        const int col = (w << 4) + l15;
        const float bias = b1[col];
        #pragma unroll
        for (int mf = 0; mf < 2; ++mf) {
            const int rbase = (mf << 4) + (l4 << 2);
            #pragma unroll
            for (int rr = 0; rr < 4; ++rr) {
                const int r = rbase + rr;
                float v = acc[mf][rr] + bias;
                v = v > 0.f ? v : 0.f;
                hbuf[r * 128 + (col ^ ((r & 7) << 2))] = v;
            }
        }
    }
    __syncthreads();

    // ================= phase 2: logits, pure-LDS inner loop =================
    const int lr = t >> 4;               // local row 0..31
    const int eg = t & 15;               // expert group (4 experts)
    const int e0 = eg << 2;
    const int row = rowBase + lr;
    const int lsw = (lr & 7) << 2;

    float acc2[5][4];
    #pragma unroll
    for (int s = 0; s < 5; ++s)
        #pragma unroll
        for (int e = 0; e < 4; ++e) acc2[s][e] = 0.f;

    // stage hm[slot] = masked h for sample sidx (bulk, coalesced m1 stream)
    auto stage_hm = [&](int slot, int sidx) {
        #pragma unroll
        for (int j = 0; j < 2; ++j) {
            int q = t + (j << 9);            // 0..1023
            int r = q >> 5, kq = q & 31;
            float4 mu = *(const float4*)(m1 + (size_t)sidx * (B_ROWS * 128)
                                            + (((size_t)(rowBase + r)) << 7) + (kq << 2));
            int off = r * 128 + ((kq << 2) ^ ((r & 7) << 2));
            float4 h4 = *(const float4*)(hbuf + off);
            float4 hm4;
            hm4.x = (mu.x >= 0.3f) ? h4.x * SCALE : 0.f;
            hm4.y = (mu.y >= 0.3f) ? h4.y * SCALE : 0.f;
            hm4.z = (mu.z >= 0.3f) ? h4.z * SCALE : 0.f;
            hm4.w = (mu.w >= 0.3f) ? h4.w * SCALE : 0.f;
            *(float4*)(hmb + (slot << 12) + off) = hm4;
        }
    };

    // stage W2 (32 KB, contiguous copy) once
    #pragma unroll
    for (int j = 0; j < 4; ++j) {
        int q = t + (j << 9);                // 0..2047 float4s
        *(float4*)(w2s + (q << 2)) = *(const float4*)(w2 + (q << 2));
    }
    stage_hm(0, 0);
    stage_hm(1, 1);
    __syncthreads();

    for (int p = 0; p < 3; ++p) {
        const int s0 = p << 1;
        const int ns = (p == 2) ? 1 : 2;
        const float* hm0 = hmb + lr * 128;
        const float* hm1 = hmb + 4096 + lr * 128;
        for (int kq = 0; kq < 32; ++kq) {
            const int hoff = (kq << 2) ^ lsw;
            float4 a0 = *(const float4*)(hm0 + hoff);
            float ha[4] = {a0.x, a0.y, a0.z, a0.w};
            float w2v[4][4];
            #pragma unroll
            for (int kk = 0; kk < 4; ++kk) {
                float4 wa = *(const float4*)(w2s + (((kq << 2) + kk) << 6) + e0);
                w2v[kk][0] = wa.x; w2v[kk][1] = wa.y; w2v[kk][2] = wa.z; w2v[kk][3] = wa.w;
            }
            #pragma unroll
            for (int kk = 0; kk < 4; ++kk)       // k ascending per accumulator
                #pragma unroll
                for (int e = 0; e < 4; ++e)
                    acc2[s0][e] += ha[kk] * w2v[kk][e];
            if (ns == 2) {
                float4 a1 = *(const float4*)(hm1 + hoff);
                float hb[4] = {a1.x, a1.y, a1.z, a1.w};
                #pragma unroll
                for (int kk = 0; kk < 4; ++kk)
                    #pragma unroll
                    for (int e = 0; e < 4; ++e)
                        acc2[s0 + 1][e] += hb[kk] * w2v[kk][e];
            }
        }
        __syncthreads();                      // all reads of hm done
        if (p < 2) {
            stage_hm(0, (p << 1) + 2);
            if (p == 0) stage_hm(1, 3);
            __syncthreads();                  // hm ready for next pair
        }
    }

    // +b2, mask2*scale, park in lgs (aliases hm/w2s head; FMA done + barrier)
    {
        float4 ba = *(const float4*)(b2 + e0);
        float bv4[4] = {ba.x, ba.y, ba.z, ba.w};
        #pragma unroll
        for (int s = 0; s < 5; ++s) {
            const float* m2p = m2 + ((size_t)s * B_ROWS + row) * 64 + e0;
            float4 ma = *(const float4*)m2p;
            float mk[4] = {ma.x, ma.y, ma.z, ma.w};
            float lv[4];
            #pragma unroll
            for (int e = 0; e < 4; ++e) {
                float v = acc2[s][e] + bv4[e];
                lv[e] = (mk[e] >= 0.3f) ? v * SCALE : 0.f;
            }
            *(float4*)(lgs + ((s << 5) + lr) * 64 + e0) =
                make_float4(lv[0], lv[1], lv[2], lv[3]);
        }
    }
    __syncthreads();

    // ================= phase 3: stats, wave per 4 rows =================
    for (int r4 = 0; r4 < 4; ++r4) {
        const int r = (w << 2) + r4;
        float l[5], p[5];
        #pragma unroll
        for (int s = 0; s < 5; ++s)
            l[s] = lgs[((s << 5) + r) * 64 + lane];

        float ml = ((((l[0] + l[1]) + l[2]) + l[3]) + l[4]) / 5.0f;

        #pragma unroll
        for (int s = 0; s < 5; ++s) {
            float mx = wave_max(l[s]);
            float ev = expf(l[s] - mx);
            float sm = wave_sum(ev);
            p[s] = ev / sm;
        }

        float mx = wave_max(ml);
        float ev = expf(ml - mx);
        float sm = wave_sum(ev);
        float prob = ev / sm;

        float mean = ((((p[0] + p[1]) + p[2]) + p[3]) + p[4]) / 5.0f;
        float var = 0.f;
        #pragma unroll
        for (int s = 0; s < 5; ++s) { float d = p[s] - mean; var += d * d; }
        float sd = sqrtf(var * 0.25f);
        float unc = wave_sum(sd) / 64.0f;

        float pv = prob;
        float vv[4]; int vi[4];
        #pragma unroll
        for (int q = 0; q < 4; ++q) {
            float bvx = pv; int bi = lane;
            #pragma unroll
            for (int m = 1; m < 64; m <<= 1) {
                float ov = __shfl_xor(bvx, m, 64);
                int oi = __shfl_xor(bi, m, 64);
                if (ov > bvx || (ov == bvx && oi < bi)) { bvx = ov; bi = oi; }
            }
            vv[q] = bvx; vi[q] = bi;
            if (lane == bi) pv = -1.f;
        }

        if (lane == 0) {
            int grow = rowBase + r;
            bool ug = unc > 0.3f;
            float4 fi = make_float4((float)vi[0], (float)vi[1],
                                    ug ? (float)vi[2] : -1.f,
                                    ug ? (float)vi[3] : -1.f);
            *(float4*)(out + (size_t)grow * 4) = fi;
            float4 fp = make_float4(vv[0], vv[1],
                                    ug ? vv[2] : 0.f,
                                    ug ? vv[3] : 0.f);
            *(float4*)(out + 65536 + (size_t)grow * 4) = fp;
            out[131072 + grow] = unc;
        }
    }
}

extern "C" void kernel_launch(void* const* d_in, const int* in_sizes, int n_in,
                              void* d_out, int out_size, void* d_ws, size_t ws_size,
                              hipStream_t stream) {
    const float* x  = (const float*)d_in[0];
    const float* W1 = (const float*)d_in[1];
    const float* b1 = (const float*)d_in[2];
    const float* W2 = (const float*)d_in[3];
    const float* b2 = (const float*)d_in[4];
    const float* m1 = (const float*)d_in[5];
    const float* m2 = (const float*)d_in[6];
    float* out = (float*)d_out;
    char* ws = (char*)d_ws;

    unsigned short* w1h = (unsigned short*)ws;                // 1 MB
    unsigned short* w1l = (unsigned short*)(ws + (1 << 20));  // 1 MB

    k_prep <<<2048, 256, 0, stream>>>(W1, w1h, w1l);
    k_fused<<<512,  512, 0, stream>>>(x, w1h, w1l, b1, W2, b2, m1, m2, out);
}